// Round 1
// baseline (91.690 us; speedup 1.0000x reference)
//
#include <hip/hip_runtime.h>
#include <hip/hip_bf16.h>

typedef __attribute__((ext_vector_type(8))) short short8;
typedef __attribute__((ext_vector_type(4))) float f32x4;

static constexpr int Bn = 8, Sn = 4096, Dn = 2048, Rn = 64;
static constexpr int BM = 64;   // rows per block (4 waves x 16)
static constexpr int KC = 64;   // K-chunk staged per barrier

__device__ __forceinline__ unsigned short f2bf(float f) {
    unsigned u = __builtin_bit_cast(unsigned, f);
    u += 0x7FFFu + ((u >> 16) & 1u);          // RTNE
    return (unsigned short)(u >> 16);
}
__device__ __forceinline__ float bf2f(unsigned short h) {
    unsigned u = (unsigned)h << 16;
    return __builtin_bit_cast(float, u);
}

__global__ __launch_bounds__(256, 2)
void batch_lora_kernel(const float* __restrict__ X, const float* __restrict__ W,
                       float* __restrict__ O) {
    // W chunk, bf16, pre-arranged in MFMA B-fragment order:
    // [ks(2)][nt(4)][lane(64)][f(8)]  -> 8 KB
    __shared__ unsigned short wlds[2 * 4 * 64 * 8];

    const int blk  = blockIdx.x;
    const int b    = blk >> 6;            // 64 blocks per batch
    const int m0   = (blk & 63) * BM;
    const int tid  = threadIdx.x;
    const int wid  = tid >> 6;            // wave 0..3
    const int lane = tid & 63;
    const int l15  = lane & 15;
    const int g    = lane >> 4;           // k-group 0..3

    const float* __restrict__ xrow = X + (size_t)b * (Sn * Dn)
                                       + (size_t)(m0 + wid * 16 + l15) * Dn + g * 8;
    const float* __restrict__ wb = W + (size_t)b * (Dn * Rn);

    f32x4 acc[4];
#pragma unroll
    for (int i = 0; i < 4; ++i) acc[i] = f32x4{0.f, 0.f, 0.f, 0.f};

    for (int kb = 0; kb < Dn; kb += KC) {
        // ---- stage bf16(W[kb:kb+KC, 0:64]) into fragment order ----
#pragma unroll
        for (int i = 0; i < 4; ++i) {
            const int e  = 4 * (tid + 256 * i);   // linear elem in chunk
            const int kk = e >> 6;                // k within chunk 0..63
            const int c  = e & 63;                // col, multiple of 4
            const float4 w4 = *reinterpret_cast<const float4*>(
                wb + (size_t)(kb + kk) * Rn + c);
            const int ks = kk >> 5;
            const int k5 = kk & 31;
            const int nt = c >> 4;
            const int f  = k5 & 7;
            const int lw = 16 * (k5 >> 3) + (c & 15);
            unsigned short* dst = &wlds[((ks * 4 + nt) * 64 + lw) * 8 + f];
            dst[0 * 8] = f2bf(w4.x);
            dst[1 * 8] = f2bf(w4.y);
            dst[2 * 8] = f2bf(w4.z);
            dst[3 * 8] = f2bf(w4.w);
        }
        __syncthreads();

        // ---- compute: 2 k-steps of K=32 ----
#pragma unroll
        for (int ks = 0; ks < 2; ++ks) {
            const float* ap = xrow + kb + ks * 32;
            const float4 a0 = *reinterpret_cast<const float4*>(ap);
            const float4 a1 = *reinterpret_cast<const float4*>(ap + 4);
            const float av[8] = {a0.x, a0.y, a0.z, a0.w, a1.x, a1.y, a1.z, a1.w};
            short8 ahi, alo;
#pragma unroll
            for (int j = 0; j < 8; ++j) {
                const unsigned short h = f2bf(av[j]);
                ahi[j] = (short)h;
                alo[j] = (short)f2bf(av[j] - bf2f(h));   // split-precision low part
            }
#pragma unroll
            for (int nt = 0; nt < 4; ++nt) {
                const short8 bhi = *reinterpret_cast<const short8*>(
                    &wlds[((ks * 4 + nt) * 64 + lane) * 8]);
                acc[nt] = __builtin_amdgcn_mfma_f32_16x16x32_bf16(ahi, bhi, acc[nt], 0, 0, 0);
                acc[nt] = __builtin_amdgcn_mfma_f32_16x16x32_bf16(alo, bhi, acc[nt], 0, 0, 0);
            }
        }
        __syncthreads();
    }

    // ---- epilogue: C/D layout col=lane&15, row=(lane>>4)*4+reg ----
    float* __restrict__ ob = O + (size_t)b * (Sn * Rn) + (size_t)(m0 + wid * 16) * Rn;
    const int r0 = g * 4;
#pragma unroll
    for (int nt = 0; nt < 4; ++nt) {
#pragma unroll
        for (int r = 0; r < 4; ++r) {
            ob[(size_t)(r0 + r) * Rn + nt * 16 + l15] = acc[nt][r];
        }
    }
}

extern "C" void kernel_launch(void* const* d_in, const int* in_sizes, int n_in,
                              void* d_out, int out_size, void* d_ws, size_t ws_size,
                              hipStream_t stream) {
    const float* x = (const float*)d_in[0];
    const float* w = (const float*)d_in[1];
    float* out = (float*)d_out;
    dim3 grid(Bn * (Sn / BM));   // 512 blocks -> 2 per CU
    dim3 block(256);
    batch_lora_kernel<<<grid, block, 0, stream>>>(x, w, out);
}

// Round 2
// 67.998 us; speedup vs baseline: 1.3484x; 1.3484x over previous
//
#include <hip/hip_runtime.h>
#include <hip/hip_bf16.h>

typedef __attribute__((ext_vector_type(8))) short short8;
typedef __attribute__((ext_vector_type(4))) float f32x4;

static constexpr int Bn = 8, Sn = 4096, Dn = 2048, Rn = 64;
static constexpr int BM = 64;                    // rows per block (4 waves x 16)
static constexpr int NCHUNK = Dn / 64;           // 32 K-chunks of 64
static constexpr int WF_PER_B = NCHUNK * 4096;   // shorts per batch (131072 = 256 KB)

__device__ __forceinline__ unsigned short f2bf(float f) {
    unsigned u = __builtin_bit_cast(unsigned, f);
    u += 0x7FFFu + ((u >> 16) & 1u);             // RTNE
    return (unsigned short)(u >> 16);
}
__device__ __forceinline__ float bf2f(unsigned short h) {
    unsigned u = (unsigned)h << 16;
    return __builtin_bit_cast(float, u);
}

// ---------------- prep: W fp32 [b][k][r] -> bf16, MFMA B-fragment order ----------------
// Wf flat index: (((b*32 + c)*2 + ks)*4 + nt)*512 + lane*8 + f
// holds bf16( W[b][c*64 + ks*32 + (lane>>4)*8 + f][nt*16 + (lane&15)] )
__global__ __launch_bounds__(256) void prep_w(const float* __restrict__ W,
                                              unsigned short* __restrict__ Wf) {
    const int t    = blockIdx.x * 256 + threadIdx.x;   // 0 .. 131071
    const int lane = t & 63;
    const int nt   = (t >> 6) & 3;
    const int ks   = (t >> 8) & 1;
    const int c    = (t >> 9) & 31;
    const int b    = t >> 14;
    const int g    = lane >> 4;
    const int r    = nt * 16 + (lane & 15);
    const float* __restrict__ src =
        W + ((size_t)b * Dn + c * 64 + ks * 32 + g * 8) * Rn + r;
    short8 o;
#pragma unroll
    for (int f = 0; f < 8; ++f) o[f] = (short)f2bf(src[(size_t)f * Rn]);
    *reinterpret_cast<short8*>(Wf + (size_t)t * 8) = o;   // coalesced 16B store
}

// ---------------- main: barrier-free streaming GEMM ----------------
struct ABuf { float4 v0, v1, v2, v3; };

__device__ __forceinline__ void load_a(ABuf& A, const float* p) {
    A.v0 = *reinterpret_cast<const float4*>(p);
    A.v1 = *reinterpret_cast<const float4*>(p + 4);
    A.v2 = *reinterpret_cast<const float4*>(p + 32);
    A.v3 = *reinterpret_cast<const float4*>(p + 36);
}
__device__ __forceinline__ void load_b(short8* Bv, const unsigned short* q) {
#pragma unroll
    for (int i = 0; i < 8; ++i)
        Bv[i] = *reinterpret_cast<const short8*>(q + i * 512);
}
__device__ __forceinline__ short8 cvt8(const float4& a, const float4& b) {
    short8 h;
    h[0] = (short)f2bf(a.x); h[1] = (short)f2bf(a.y);
    h[2] = (short)f2bf(a.z); h[3] = (short)f2bf(a.w);
    h[4] = (short)f2bf(b.x); h[5] = (short)f2bf(b.y);
    h[6] = (short)f2bf(b.z); h[7] = (short)f2bf(b.w);
    return h;
}
__device__ __forceinline__ void compute_chunk(const ABuf& A, const short8* Bv, f32x4* acc) {
    const short8 h0 = cvt8(A.v0, A.v1);   // k = ks0: g*8 + 0..7
    const short8 h1 = cvt8(A.v2, A.v3);   // k = ks1
#pragma unroll
    for (int nt = 0; nt < 4; ++nt)
        acc[nt] = __builtin_amdgcn_mfma_f32_16x16x32_bf16(h0, Bv[nt], acc[nt], 0, 0, 0);
#pragma unroll
    for (int nt = 0; nt < 4; ++nt)
        acc[nt] = __builtin_amdgcn_mfma_f32_16x16x32_bf16(h1, Bv[4 + nt], acc[nt], 0, 0, 0);
}

__global__ __launch_bounds__(256, 2)
void lora_main(const float* __restrict__ X, const unsigned short* __restrict__ Wf,
               float* __restrict__ O) {
    const int blk  = blockIdx.x;
    const int b    = blk >> 6;
    const int m0   = (blk & 63) * BM;
    const int tid  = threadIdx.x;
    const int wid  = tid >> 6;
    const int lane = tid & 63;
    const int l15  = lane & 15;
    const int g    = lane >> 4;

    const float* xp = X + (size_t)b * (Sn * Dn)
                        + (size_t)(m0 + wid * 16 + l15) * Dn + g * 8;
    const unsigned short* bp = Wf + (size_t)b * WF_PER_B + lane * 8;

    f32x4 acc[4];
#pragma unroll
    for (int i = 0; i < 4; ++i) acc[i] = f32x4{0.f, 0.f, 0.f, 0.f};

    ABuf A0, A1;
    short8 B0[8], B1[8];
    load_a(A0, xp);
    load_b(B0, bp);

    for (int c = 0; c < NCHUNK; c += 2) {
        // prefetch chunk c+1
        load_a(A1, xp + 64);
        load_b(B1, bp + 4096);
        compute_chunk(A0, B0, acc);

        // prefetch chunk c+2 (clamped dummy on last iteration — L2 re-hit, unused)
        const bool last = (c + 2 >= NCHUNK);
        const float*          xp2 = last ? xp : (xp + 128);
        const unsigned short* bp2 = last ? bp : (bp + 8192);
        load_a(A0, xp2);
        load_b(B0, bp2);
        compute_chunk(A1, B1, acc);

        xp += 128;
        bp += 8192;
    }

    // epilogue: C/D layout col=lane&15, row=(lane>>4)*4+reg
    float* __restrict__ ob = O + (size_t)b * (Sn * Rn) + (size_t)(m0 + wid * 16) * Rn;
    const int r0 = g * 4;
#pragma unroll
    for (int nt = 0; nt < 4; ++nt) {
#pragma unroll
        for (int r = 0; r < 4; ++r) {
            ob[(size_t)(r0 + r) * Rn + nt * 16 + l15] = acc[nt][r];
        }
    }
}

// ---------------- fallback (round-1 kernel) if ws is too small ----------------
__global__ __launch_bounds__(256, 2)
void batch_lora_fused(const float* __restrict__ X, const float* __restrict__ W,
                      float* __restrict__ O) {
    __shared__ unsigned short wlds[2 * 4 * 64 * 8];
    const int blk  = blockIdx.x;
    const int b    = blk >> 6;
    const int m0   = (blk & 63) * BM;
    const int tid  = threadIdx.x;
    const int wid  = tid >> 6;
    const int lane = tid & 63;
    const int l15  = lane & 15;
    const int g    = lane >> 4;
    const float* __restrict__ xrow = X + (size_t)b * (Sn * Dn)
                                       + (size_t)(m0 + wid * 16 + l15) * Dn + g * 8;
    const float* __restrict__ wb = W + (size_t)b * (Dn * Rn);
    f32x4 acc[4];
#pragma unroll
    for (int i = 0; i < 4; ++i) acc[i] = f32x4{0.f, 0.f, 0.f, 0.f};
    for (int kb = 0; kb < Dn; kb += 64) {
#pragma unroll
        for (int i = 0; i < 4; ++i) {
            const int e  = 4 * (tid + 256 * i);
            const int kk = e >> 6;
            const int cc = e & 63;
            const float4 w4 = *reinterpret_cast<const float4*>(
                wb + (size_t)(kb + kk) * Rn + cc);
            const int ks = kk >> 5;
            const int k5 = kk & 31;
            const int nt = cc >> 4;
            const int f  = k5 & 7;
            const int lw = 16 * (k5 >> 3) + (cc & 15);
            unsigned short* dst = &wlds[((ks * 4 + nt) * 64 + lw) * 8 + f];
            dst[0 * 8] = f2bf(w4.x); dst[1 * 8] = f2bf(w4.y);
            dst[2 * 8] = f2bf(w4.z); dst[3 * 8] = f2bf(w4.w);
        }
        __syncthreads();
#pragma unroll
        for (int ks = 0; ks < 2; ++ks) {
            const float* ap = xrow + kb + ks * 32;
            const float4 a0 = *reinterpret_cast<const float4*>(ap);
            const float4 a1 = *reinterpret_cast<const float4*>(ap + 4);
            const short8 ahi = cvt8(a0, a1);
#pragma unroll
            for (int nt = 0; nt < 4; ++nt) {
                const short8 bhi = *reinterpret_cast<const short8*>(
                    &wlds[((ks * 4 + nt) * 64 + lane) * 8]);
                acc[nt] = __builtin_amdgcn_mfma_f32_16x16x32_bf16(ahi, bhi, acc[nt], 0, 0, 0);
            }
        }
        __syncthreads();
    }
    float* __restrict__ ob = O + (size_t)b * (Sn * Rn) + (size_t)(m0 + wid * 16) * Rn;
    const int r0 = g * 4;
#pragma unroll
    for (int nt = 0; nt < 4; ++nt)
#pragma unroll
        for (int r = 0; r < 4; ++r)
            ob[(size_t)(r0 + r) * Rn + nt * 16 + l15] = acc[nt][r];
}

extern "C" void kernel_launch(void* const* d_in, const int* in_sizes, int n_in,
                              void* d_out, int out_size, void* d_ws, size_t ws_size,
                              hipStream_t stream) {
    const float* x = (const float*)d_in[0];
    const float* w = (const float*)d_in[1];
    float* out = (float*)d_out;
    const size_t wf_bytes = (size_t)Bn * WF_PER_B * sizeof(unsigned short);  // 2 MiB
    if (ws_size >= wf_bytes) {
        unsigned short* wf = (unsigned short*)d_ws;
        prep_w<<<dim3(512), dim3(256), 0, stream>>>(w, wf);
        lora_main<<<dim3(Bn * (Sn / BM)), dim3(256), 0, stream>>>(x, wf, out);
    } else {
        batch_lora_fused<<<dim3(Bn * (Sn / BM)), dim3(256), 0, stream>>>(x, w, out);
    }
}